// Round 1
// baseline (7055.417 us; speedup 1.0000x reference)
//
#include <hip/hip_runtime.h>
#include <hip/hip_bf16.h>

#define H1 1024
#define FOURH 4096
#define BATCH 512
#define SEQ 64
#define DIN 128
#define TDEC 8

#define BM 64
#define BN 128
#define BK 64

typedef float f32x4 __attribute__((ext_vector_type(4)));
typedef __bf16 bf16x4 __attribute__((ext_vector_type(4)));
typedef __bf16 bf16x8 __attribute__((ext_vector_type(8)));

// ---------------------------------------------------------------------------
// gates[512][4096] = A0[512][K0] * B0[4096][K0]^T + A1[512][K1] * B1[4096][K1]^T + bias
// A given fp32 row-major (lda), B given fp32 row-major [4096][K] (ldb == K).
// Internally: split each fp32 operand into bf16 hi/lo during LDS staging and
// accumulate 3 MFMA terms (hi*hi + hi*lo + lo*hi) -> fp32-quality result.
// Tile: BM=64 x BN=128 x BK=64, 256 threads (4 waves, each 32x64).
// ---------------------------------------------------------------------------
__global__ __launch_bounds__(256) void gemm2_split(
    const float* __restrict__ A0, int lda0, const float* __restrict__ B0, int K0,
    const float* __restrict__ A1, int lda1, const float* __restrict__ B1, int K1,
    const float* __restrict__ bias, float* __restrict__ out)
{
    __shared__ __bf16 sAh[BM * BK];
    __shared__ __bf16 sAl[BM * BK];
    __shared__ __bf16 sBh[BN * BK];
    __shared__ __bf16 sBl[BN * BK];

    const int tid  = threadIdx.x;
    const int lane = tid & 63;
    const int wid  = tid >> 6;       // 0..3
    const int wm   = wid >> 1;       // wave row (0..1) -> 32 rows each
    const int wn   = wid & 1;        // wave col (0..1) -> 64 cols each
    const int bn   = blockIdx.x;     // 0..31
    const int bm   = blockIdx.y;     // 0..7

    f32x4 acc[2][4];
#pragma unroll
    for (int mf = 0; mf < 2; ++mf)
#pragma unroll
        for (int nf = 0; nf < 4; ++nf)
            acc[mf][nf] = (f32x4){0.f, 0.f, 0.f, 0.f};

    for (int pair = 0; pair < 2; ++pair) {
        const float* A = pair ? A1 : A0;
        const float* B = pair ? B1 : B0;
        const int lda  = pair ? lda1 : lda0;
        const int K    = pair ? K1 : K0;

        for (int ko = 0; ko < K; ko += BK) {
            // ---- global loads (fp32) into registers ----
            f32x4 ar[4];
#pragma unroll
            for (int j = 0; j < 4; ++j) {
                int i  = tid + 256 * j;          // 0..1023 over [64 rows][16 f4]
                int r  = i >> 4;
                int c4 = i & 15;
                ar[j] = *(const f32x4*)(A + (size_t)(bm * BM + r) * lda + ko + c4 * 4);
            }
            f32x4 br[8];
#pragma unroll
            for (int j = 0; j < 8; ++j) {
                int i  = tid + 256 * j;          // 0..2047 over [128 rows][16 f4]
                int r  = i >> 4;
                int c4 = i & 15;
                br[j] = *(const f32x4*)(B + (size_t)(bn * BN + r) * K + ko + c4 * 4);
            }

            __syncthreads();   // previous iteration's ds_reads complete

            // ---- convert to bf16 hi/lo and store to swizzled LDS ----
#pragma unroll
            for (int j = 0; j < 4; ++j) {
                int i = tid + 256 * j;
                int r = i >> 4;
                int k = (i & 15) * 4;
                bf16x4 hi, lo;
#pragma unroll
                for (int e = 0; e < 4; ++e) {
                    float xx  = ar[j][e];
                    __bf16 h  = (__bf16)xx;
                    hi[e]     = h;
                    lo[e]     = (__bf16)(xx - (float)h);
                }
                int idx = (r * BK + k) ^ ((r & 7) << 3);   // 16B-slot XOR swizzle
                *(bf16x4*)&sAh[idx] = hi;
                *(bf16x4*)&sAl[idx] = lo;
            }
#pragma unroll
            for (int j = 0; j < 8; ++j) {
                int i = tid + 256 * j;
                int r = i >> 4;
                int k = (i & 15) * 4;
                bf16x4 hi, lo;
#pragma unroll
                for (int e = 0; e < 4; ++e) {
                    float xx  = br[j][e];
                    __bf16 h  = (__bf16)xx;
                    hi[e]     = h;
                    lo[e]     = (__bf16)(xx - (float)h);
                }
                int idx = (r * BK + k) ^ ((r & 7) << 3);
                *(bf16x4*)&sBh[idx] = hi;
                *(bf16x4*)&sBl[idx] = lo;
            }

            __syncthreads();   // LDS tile visible to all waves

            // ---- MFMA: 3-term split accumulate ----
#pragma unroll
            for (int kf = 0; kf < 2; ++kf) {
                int kb = kf * 32 + (lane >> 4) * 8;
                bf16x8 ah[2], al[2], bh[4], bl[4];
#pragma unroll
                for (int mf = 0; mf < 2; ++mf) {
                    int row = wm * 32 + mf * 16 + (lane & 15);
                    int idx = (row * BK + kb) ^ ((row & 7) << 3);
                    ah[mf] = *(const bf16x8*)&sAh[idx];
                    al[mf] = *(const bf16x8*)&sAl[idx];
                }
#pragma unroll
                for (int nf = 0; nf < 4; ++nf) {
                    int rn  = wn * 64 + nf * 16 + (lane & 15);
                    int idx = (rn * BK + kb) ^ ((rn & 7) << 3);
                    bh[nf] = *(const bf16x8*)&sBh[idx];
                    bl[nf] = *(const bf16x8*)&sBl[idx];
                }
#pragma unroll
                for (int mf = 0; mf < 2; ++mf)
#pragma unroll
                    for (int nf = 0; nf < 4; ++nf) {
                        acc[mf][nf] = __builtin_amdgcn_mfma_f32_16x16x32_bf16(
                            ah[mf], bh[nf], acc[mf][nf], 0, 0, 0);
                        acc[mf][nf] = __builtin_amdgcn_mfma_f32_16x16x32_bf16(
                            ah[mf], bl[nf], acc[mf][nf], 0, 0, 0);
                        acc[mf][nf] = __builtin_amdgcn_mfma_f32_16x16x32_bf16(
                            al[mf], bh[nf], acc[mf][nf], 0, 0, 0);
                    }
            }
        }
    }

    // ---- epilogue: add bias, store fp32 gates ----
    // C/D layout (m89-verified): col = lane&15, row = (lane>>4)*4 + j
#pragma unroll
    for (int mf = 0; mf < 2; ++mf)
#pragma unroll
        for (int nf = 0; nf < 4; ++nf) {
            int row0 = bm * BM + wm * 32 + mf * 16 + (lane >> 4) * 4;
            int col  = bn * BN + wn * 64 + nf * 16 + (lane & 15);
            float bv = bias[col];
#pragma unroll
            for (int j = 0; j < 4; ++j)
                out[(size_t)(row0 + j) * FOURH + col] = acc[mf][nf][j] + bv;
        }
}

// ---------------------------------------------------------------------------
// Pointwise LSTM cell: gates[512][4096] (i,f,g,o blocks), c in/out, h out.
// ---------------------------------------------------------------------------
__global__ __launch_bounds__(256) void lstm_cell_k(
    const float* __restrict__ gates, float* __restrict__ c, float* __restrict__ h)
{
    int idx = blockIdx.x * 256 + threadIdx.x;     // 0 .. 512*1024-1
    int b   = idx >> 10;
    int u   = idx & 1023;
    const float* g = gates + (size_t)b * FOURH;
    float gi = g[u];
    float gf = g[u + H1];
    float gg = g[u + 2 * H1];
    float go = g[u + 3 * H1];
    float si = 1.f / (1.f + expf(-gi));
    float sf = 1.f / (1.f + expf(-gf));
    float so = 1.f / (1.f + expf(-go));
    float cc = sf * c[idx] + si * tanhf(gg);
    c[idx] = cc;
    h[idx] = so * tanhf(cc);
}

// ---------------------------------------------------------------------------
// Output head: out[b][o] = h[b]·W_out[o] + b_out[o], duplicated at +16.
// ---------------------------------------------------------------------------
__global__ __launch_bounds__(256) void head_k(
    const float* __restrict__ h, const float* __restrict__ W,
    const float* __restrict__ bo, float* __restrict__ out)
{
    int idx = blockIdx.x * 256 + threadIdx.x;     // 0 .. 8191
    int b = idx >> 4;
    int o = idx & 15;
    const f32x4* hv = (const f32x4*)(h + (size_t)b * H1);
    const f32x4* wv = (const f32x4*)(W + (size_t)o * H1);
    float s = bo[o];
#pragma unroll 4
    for (int k = 0; k < H1 / 4; ++k) {
        f32x4 a = hv[k];
        f32x4 w = wv[k];
        s += a[0] * w[0] + a[1] * w[1] + a[2] * w[2] + a[3] * w[3];
    }
    out[(size_t)b * 32 + o]      = s;
    out[(size_t)b * 32 + 16 + o] = s;
}

// ---------------------------------------------------------------------------
extern "C" void kernel_launch(void* const* d_in, const int* in_sizes, int n_in,
                              void* d_out, int out_size, void* d_ws, size_t ws_size,
                              hipStream_t stream)
{
    const float* x    = (const float*)d_in[0];
    const float* Wih0 = (const float*)d_in[1];
    const float* Whh0 = (const float*)d_in[2];
    const float* b0   = (const float*)d_in[3];
    const float* Wih1 = (const float*)d_in[4];
    const float* Whh1 = (const float*)d_in[5];
    const float* b1   = (const float*)d_in[6];
    const float* dWih = (const float*)d_in[7];
    const float* dWhh = (const float*)d_in[8];
    const float* db   = (const float*)d_in[9];
    const float* Wout = (const float*)d_in[10];
    const float* bout = (const float*)d_in[11];
    // d_in[12] = decode_steps (== 8, hardcoded as TDEC)

    float* ws    = (float*)d_ws;
    float* gates = ws;                              // 512*4096
    float* h0a   = gates + (size_t)BATCH * FOURH;   // 512*1024 each below
    float* h0b   = h0a + (size_t)BATCH * H1;
    float* h1    = h0b + (size_t)BATCH * H1;
    float* c0    = h1 + (size_t)BATCH * H1;
    float* c1    = c0 + (size_t)BATCH * H1;

    const size_t sbytes = (size_t)BATCH * H1 * sizeof(float);
    hipMemsetAsync(h0a, 0, sbytes, stream);
    hipMemsetAsync(h1, 0, sbytes, stream);
    hipMemsetAsync(c0, 0, sbytes, stream);
    hipMemsetAsync(c1, 0, sbytes, stream);

    dim3 grid(FOURH / BN, BATCH / BM);   // (32, 8)
    dim3 blk(256);
    dim3 cgrid((BATCH * H1) / 256);      // 2048

    float* hc = h0a;   // current layer-0 h
    float* hn = h0b;   // next layer-0 h

    // ---- encoder: layers interleaved per timestep ----
    for (int t = 0; t < SEQ; ++t) {
        gemm2_split<<<grid, blk, 0, stream>>>(x + (size_t)t * DIN, SEQ * DIN, Wih0, DIN,
                                              hc, H1, Whh0, H1, b0, gates);
        lstm_cell_k<<<cgrid, blk, 0, stream>>>(gates, c0, hn);
        gemm2_split<<<grid, blk, 0, stream>>>(hn, H1, Wih1, H1,
                                              h1, H1, Whh1, H1, b1, gates);
        lstm_cell_k<<<cgrid, blk, 0, stream>>>(gates, c1, h1);
        float* tmp = hc; hc = hn; hn = tmp;
    }

    // ---- decoder: x_in = h1 (== ys1[-1] initially, then fed-back output) ----
    const float* dWih1 = dWih + (size_t)FOURH * H1;
    const float* dWhh1 = dWhh + (size_t)FOURH * H1;
    const float* db1v  = db + FOURH;
    for (int s = 0; s < TDEC; ++s) {
        gemm2_split<<<grid, blk, 0, stream>>>(h1, H1, dWih, H1,
                                              hc, H1, dWhh, H1, db, gates);
        lstm_cell_k<<<cgrid, blk, 0, stream>>>(gates, c0, hn);
        gemm2_split<<<grid, blk, 0, stream>>>(hn, H1, dWih1, H1,
                                              h1, H1, dWhh1, H1, db1v, gates);
        lstm_cell_k<<<cgrid, blk, 0, stream>>>(gates, c1, h1);
        float* tmp = hc; hc = hn; hn = tmp;
    }

    // ---- output head ----
    head_k<<<dim3(32), blk, 0, stream>>>(h1, Wout, bout, (float*)d_out);
}

// Round 3
// 6036.852 us; speedup vs baseline: 1.1687x; 1.1687x over previous
//
#include <hip/hip_runtime.h>
#include <hip/hip_bf16.h>

#define H1 1024
#define FOURH 4096
#define BATCH 512
#define SEQ 64
#define DIN 128
#define TDEC 8

typedef float f32x4 __attribute__((ext_vector_type(4)));
typedef __bf16 bf16x4 __attribute__((ext_vector_type(4)));
typedef __bf16 bf16x8 __attribute__((ext_vector_type(8)));

// ===========================================================================
// NEW PATH
// ===========================================================================

// global->LDS direct, 16B per lane. LDS dest is wave-uniform base + lane*16.
__device__ __forceinline__ void gl_lds16(const void* g, void* l) {
    __builtin_amdgcn_global_load_lds(
        (const __attribute__((address_space(1))) unsigned int*)g,
        (__attribute__((address_space(3))) unsigned int*)l, 16, 0, 0);
}

// fp32 [R][K] -> bf16 pair [R][2K] (hi | lo).  K = 4<<k4shift elements.
__global__ __launch_bounds__(256) void conv_pair_k(
    const float* __restrict__ src, __bf16* __restrict__ dst,
    int total4, int k4shift)
{
    int i = blockIdx.x * 256 + threadIdx.x;
    if (i >= total4) return;
    int K4 = 1 << k4shift;
    int r  = i >> k4shift;
    int c4 = i & (K4 - 1);
    int K  = K4 * 4;
    f32x4 v = *(const f32x4*)(src + (size_t)r * K + c4 * 4);
    bf16x4 hi, lo;
#pragma unroll
    for (int e = 0; e < 4; ++e) {
        __bf16 h = (__bf16)v[e];
        hi[e] = h;
        lo[e] = (__bf16)(v[e] - (float)h);
    }
    __bf16* d = dst + (size_t)r * 2 * K;
    *(bf16x4*)(d + c4 * 4)     = hi;
    *(bf16x4*)(d + K + c4 * 4) = lo;
}

// ---------------------------------------------------------------------------
// out_partial[512][4096] (+=bias later in cell) =
//   sum over 6 segments: {Ah*Bh, Ah*Bl, Al*Bh} x {pair0, pair1}
// A pair layout: [rows][lda] with hi at col [0,K), lo at [aLo, aLo+K).
// B pair layout: [4096][2K] hi [0,K), lo [K,2K).
// Tile BM=BN=128, BK=64; 4 waves, each 64x64 (4x4 of 16x16x32 MFMA frags).
// K-split 2 via blockIdx.z -> g0 / g1 partial buffers.
// Triple-buffered LDS staging via global_load_lds with XOR-swizzled source.
// ---------------------------------------------------------------------------
__global__ __launch_bounds__(256) void gemm_pair_lds(
    const __bf16* __restrict__ a0, int lda0, int alo0, int k0,
    const __bf16* __restrict__ b0, int ldb0,
    const __bf16* __restrict__ a1, int lda1, int alo1, int k1,
    const __bf16* __restrict__ b1, int ldb1,
    float* __restrict__ g0, float* __restrict__ g1)
{
    extern __shared__ char smem[];            // 3 * 32KB (A 16KB + B 16KB)
    const int tid  = threadIdx.x;
    const int lane = tid & 63;
    const int w    = tid >> 6;                // wave 0..3
    const int wm   = w >> 1, wn = w & 1;
    const int bn   = blockIdx.x, bm = blockIdx.y, ks = blockIdx.z;
    float* out = ks ? g1 : g0;

    const int kh0 = k0 >> 1, kh1 = k1 >> 1;
    const int n0 = kh0 >> 6, n1 = kh1 >> 6;   // BK=64 iters per segment
    const int n  = 3 * (n0 + n1);
    const int ksO0 = ks * kh0, ksO1 = ks * kh1;

    // staging geometry: chunk j covers rows (j*4+w)*8 .. +7 of the 128-row tile
    const int rsub = lane >> 3;               // 0..7
    const int gsw  = (lane & 7) ^ rsub;       // swizzled source granule (involution)
    int rowj[4];
#pragma unroll
    for (int j = 0; j < 4; ++j) rowj[j] = (j * 4 + w) * 8 + rsub;

    auto stagef = [&](int ii, int buf) {
        int p, t, kk;
        int n3 = 3 * n0;
        if (ii < n3) { p = 0; t = ii / n0; kk = (ii - t * n0) << 6; }
        else { int d = ii - n3; p = 1; t = d / n1; kk = (d - t * n1) << 6; }
        const __bf16* aP; const __bf16* bP; int lda, ldb, K, alo, ksO;
        if (p == 0) { aP = a0; bP = b0; lda = lda0; ldb = ldb0; K = k0; alo = alo0; ksO = ksO0; }
        else        { aP = a1; bP = b1; lda = lda1; ldb = ldb1; K = k1; alo = alo1; ksO = ksO1; }
        const __bf16* aU = aP + (size_t)(bm * 128) * lda + (t == 2 ? alo : 0) + ksO + kk;
        const __bf16* bU = bP + (size_t)(bn * 128) * ldb + (t == 1 ? K   : 0) + ksO + kk;
        char* lA = smem + buf * 32768;
        char* lB = lA + 16384;
#pragma unroll
        for (int j = 0; j < 4; ++j) {
            gl_lds16(aU + rowj[j] * lda + gsw * 8, lA + (j * 4 + w) * 1024);
            gl_lds16(bU + rowj[j] * ldb + gsw * 8, lB + (j * 4 + w) * 1024);
        }
    };

    f32x4 acc[4][4];
#pragma unroll
    for (int mf = 0; mf < 4; ++mf)
#pragma unroll
        for (int nf = 0; nf < 4; ++nf)
            acc[mf][nf] = (f32x4){0.f, 0.f, 0.f, 0.f};

    int rA[4], rB[4];
#pragma unroll
    for (int f = 0; f < 4; ++f) {
        rA[f] = wm * 64 + f * 16 + (lane & 15);
        rB[f] = wn * 64 + f * 16 + (lane & 15);
    }
    const int hi4 = lane >> 4;
    const int lsw = lane & 7;                 // row&7 == lane&7 for frag rows

    stagef(0, 0);
    stagef(1, 1);

    int buf = 0;
    for (int i = 0; i < n; ++i) {
        if (i < n - 1) asm volatile("s_waitcnt vmcnt(8)" ::: "memory");
        else           asm volatile("s_waitcnt vmcnt(0)" ::: "memory");
        __builtin_amdgcn_sched_barrier(0);
        __builtin_amdgcn_s_barrier();
        __builtin_amdgcn_sched_barrier(0);

        if (i + 2 < n) {
            int b2 = buf + 2; if (b2 >= 3) b2 -= 3;
            stagef(i + 2, b2);
        }

        char* lA = smem + buf * 32768;
        char* lB = lA + 16384;
#pragma unroll
        for (int kf = 0; kf < 2; ++kf) {
            const int gr = kf * 4 + hi4;        // granule column 0..7
            bf16x8 af[4], bfr[4];
#pragma unroll
            for (int f = 0; f < 4; ++f) {
                int sA = rA[f] * 8 + (gr ^ lsw);
                af[f]  = *(const bf16x8*)(lA + sA * 16);
                int sB = rB[f] * 8 + (gr ^ lsw);
                bfr[f] = *(const bf16x8*)(lB + sB * 16);
            }
#pragma unroll
            for (int mf = 0; mf < 4; ++mf)
#pragma unroll
                for (int nf = 0; nf < 4; ++nf)
                    acc[mf][nf] = __builtin_amdgcn_mfma_f32_16x16x32_bf16(
                        af[mf], bfr[nf], acc[mf][nf], 0, 0, 0);
        }
        __builtin_amdgcn_sched_barrier(0);
        buf = buf + 1; if (buf >= 3) buf -= 3;
    }

    // epilogue: C layout col=lane&15, row=(lane>>4)*4 + jj  (m89-verified)
#pragma unroll
    for (int mf = 0; mf < 4; ++mf)
#pragma unroll
        for (int nf = 0; nf < 4; ++nf) {
            int row0 = bm * 128 + wm * 64 + mf * 16 + hi4 * 4;
            int col  = bn * 128 + wn * 64 + nf * 16 + (lane & 15);
#pragma unroll
            for (int jj = 0; jj < 4; ++jj)
                out[(size_t)(row0 + jj) * FOURH + col] = acc[mf][nf][jj];
        }
}

// cell: gates = g0 + g1 + bias; write c and h as bf16 hi/lo pair [b][2048].
__global__ __launch_bounds__(256) void lstm_cell2_k(
    const float* __restrict__ g0, const float* __restrict__ g1,
    const float* __restrict__ bias,
    float* __restrict__ c, __bf16* __restrict__ hp)
{
    int idx = blockIdx.x * 256 + threadIdx.x;
    int b = idx >> 10, u = idx & 1023;
    size_t base = (size_t)b * FOURH + u;
    float gi = g0[base]          + g1[base]          + bias[u];
    float gf = g0[base + H1]     + g1[base + H1]     + bias[u + H1];
    float gg = g0[base + 2 * H1] + g1[base + 2 * H1] + bias[u + 2 * H1];
    float go = g0[base + 3 * H1] + g1[base + 3 * H1] + bias[u + 3 * H1];
    float si = 1.f / (1.f + expf(-gi));
    float sf = 1.f / (1.f + expf(-gf));
    float so = 1.f / (1.f + expf(-go));
    float cc = sf * c[idx] + si * tanhf(gg);
    c[idx] = cc;
    float hv = so * tanhf(cc);
    __bf16 hh = (__bf16)hv;
    hp[(size_t)b * 2048 + u]        = hh;
    hp[(size_t)b * 2048 + 1024 + u] = (__bf16)(hv - (float)hh);
}

__global__ __launch_bounds__(256) void head2_k(
    const __bf16* __restrict__ hp, const float* __restrict__ W,
    const float* __restrict__ bo, float* __restrict__ out)
{
    int idx = blockIdx.x * 256 + threadIdx.x;   // 0..8191
    int b = idx >> 4, o = idx & 15;
    const __bf16* hr = hp + (size_t)b * 2048;
    const f32x4* wv = (const f32x4*)(W + (size_t)o * H1);
    float s = bo[o];
#pragma unroll 4
    for (int k4 = 0; k4 < 128; ++k4) {
        bf16x8 vh = *(const bf16x8*)(hr + k4 * 8);
        bf16x8 vl = *(const bf16x8*)(hr + 1024 + k4 * 8);
        f32x4 w0 = wv[k4 * 2], w1 = wv[k4 * 2 + 1];
#pragma unroll
        for (int e = 0; e < 4; ++e)
            s += ((float)vh[e] + (float)vl[e]) * w0[e];
#pragma unroll
        for (int e = 4; e < 8; ++e)
            s += ((float)vh[e] + (float)vl[e]) * w1[e - 4];
    }
    out[(size_t)b * 32 + o]      = s;
    out[(size_t)b * 32 + 16 + o] = s;
}

// ===========================================================================
// FALLBACK PATH (round-1, proven) — used if ws_size is too small
// ===========================================================================
#define BM 64
#define BN 128
#define BK 64

__global__ __launch_bounds__(256) void gemm2_split(
    const float* __restrict__ A0, int lda0, const float* __restrict__ B0, int K0,
    const float* __restrict__ A1, int lda1, const float* __restrict__ B1, int K1,
    const float* __restrict__ bias, float* __restrict__ out)
{
    __shared__ __bf16 sAh[BM * BK];
    __shared__ __bf16 sAl[BM * BK];
    __shared__ __bf16 sBh[BN * BK];
    __shared__ __bf16 sBl[BN * BK];

    const int tid  = threadIdx.x;
    const int lane = tid & 63;
    const int wid  = tid >> 6;
    const int wm   = wid >> 1;
    const int wn   = wid & 1;
    const int bn   = blockIdx.x;
    const int bm   = blockIdx.y;

    f32x4 acc[2][4];
#pragma unroll
    for (int mf = 0; mf < 2; ++mf)
#pragma unroll
        for (int nf = 0; nf < 4; ++nf)
            acc[mf][nf] = (f32x4){0.f, 0.f, 0.f, 0.f};

    for (int pair = 0; pair < 2; ++pair) {
        const float* A = pair ? A1 : A0;
        const float* B = pair ? B1 : B0;
        const int lda  = pair ? lda1 : lda0;
        const int K    = pair ? K1 : K0;

        for (int ko = 0; ko < K; ko += BK) {
            f32x4 ar[4];
#pragma unroll
            for (int j = 0; j < 4; ++j) {
                int i = tid + 256 * j;
                int r = i >> 4, c4 = i & 15;
                ar[j] = *(const f32x4*)(A + (size_t)(bm * BM + r) * lda + ko + c4 * 4);
            }
            f32x4 br[8];
#pragma unroll
            for (int j = 0; j < 8; ++j) {
                int i = tid + 256 * j;
                int r = i >> 4, c4 = i & 15;
                br[j] = *(const f32x4*)(B + (size_t)(bn * BN + r) * K + ko + c4 * 4);
            }
            __syncthreads();
#pragma unroll
            for (int j = 0; j < 4; ++j) {
                int i = tid + 256 * j;
                int r = i >> 4, k = (i & 15) * 4;
                bf16x4 hi, lo;
#pragma unroll
                for (int e = 0; e < 4; ++e) {
                    float xx = ar[j][e];
                    __bf16 h = (__bf16)xx;
                    hi[e] = h; lo[e] = (__bf16)(xx - (float)h);
                }
                int idx = (r * BK + k) ^ ((r & 7) << 3);
                *(bf16x4*)&sAh[idx] = hi;
                *(bf16x4*)&sAl[idx] = lo;
            }
#pragma unroll
            for (int j = 0; j < 8; ++j) {
                int i = tid + 256 * j;
                int r = i >> 4, k = (i & 15) * 4;
                bf16x4 hi, lo;
#pragma unroll
                for (int e = 0; e < 4; ++e) {
                    float xx = br[j][e];
                    __bf16 h = (__bf16)xx;
                    hi[e] = h; lo[e] = (__bf16)(xx - (float)h);
                }
                int idx = (r * BK + k) ^ ((r & 7) << 3);
                *(bf16x4*)&sBh[idx] = hi;
                *(bf16x4*)&sBl[idx] = lo;
            }
            __syncthreads();
#pragma unroll
            for (int kf = 0; kf < 2; ++kf) {
                int kb = kf * 32 + (lane >> 4) * 8;
                bf16x8 ah[2], al[2], bh[4], bl[4];
#pragma unroll
                for (int mf = 0; mf < 2; ++mf) {
                    int row = wm * 32 + mf * 16 + (lane & 15);
                    int idx = (row * BK + kb) ^ ((row & 7) << 3);
                    ah[mf] = *(const bf16x8*)&sAh[idx];
                    al[mf] = *(const bf16x8*)&sAl[idx];
                }
#pragma unroll
                for (int nf = 0; nf < 4; ++nf) {
                    int rn  = wn * 64 + nf * 16 + (lane & 15);
                    int idx = (rn * BK + kb) ^ ((rn & 7) << 3);
                    bh[nf] = *(const bf16x8*)&sBh[idx];
                    bl[nf] = *(const bf16x8*)&sBl[idx];
                }
#pragma unroll
                for (int mf = 0; mf < 2; ++mf)
#pragma unroll
                    for (int nf = 0; nf < 4; ++nf) {
                        acc[mf][nf] = __builtin_amdgcn_mfma_f32_16x16x32_bf16(
                            ah[mf], bh[nf], acc[mf][nf], 0, 0, 0);
                        acc[mf][nf] = __builtin_amdgcn_mfma_f32_16x16x32_bf16(
                            ah[mf], bl[nf], acc[mf][nf], 0, 0, 0);
                        acc[mf][nf] = __builtin_amdgcn_mfma_f32_16x16x32_bf16(
                            al[mf], bh[nf], acc[mf][nf], 0, 0, 0);
                    }
            }
        }
    }
#pragma unroll
    for (int mf = 0; mf < 2; ++mf)
#pragma unroll
        for (int nf = 0; nf < 4; ++nf) {
            int row0 = bm * BM + wm * 32 + mf * 16 + (lane >> 4) * 4;
            int col  = bn * BN + wn * 64 + nf * 16 + (lane & 15);
            float bv = bias[col];
#pragma unroll
            for (int j = 0; j < 4; ++j)
                out[(size_t)(row0 + j) * FOURH + col] = acc[mf][nf][j] + bv;
        }
}

__global__ __launch_bounds__(256) void lstm_cell_k(
    const float* __restrict__ gates, float* __restrict__ c, float* __restrict__ h)
{
    int idx = blockIdx.x * 256 + threadIdx.x;
    int b = idx >> 10, u = idx & 1023;
    const float* g = gates + (size_t)b * FOURH;
    float gi = g[u], gf = g[u + H1], gg = g[u + 2 * H1], go = g[u + 3 * H1];
    float si = 1.f / (1.f + expf(-gi));
    float sf = 1.f / (1.f + expf(-gf));
    float so = 1.f / (1.f + expf(-go));
    float cc = sf * c[idx] + si * tanhf(gg);
    c[idx] = cc;
    h[idx] = so * tanhf(cc);
}

__global__ __launch_bounds__(256) void head_k(
    const float* __restrict__ h, const float* __restrict__ W,
    const float* __restrict__ bo, float* __restrict__ out)
{
    int idx = blockIdx.x * 256 + threadIdx.x;
    int b = idx >> 4, o = idx & 15;
    const f32x4* hv = (const f32x4*)(h + (size_t)b * H1);
    const f32x4* wv = (const f32x4*)(W + (size_t)o * H1);
    float s = bo[o];
#pragma unroll 4
    for (int k = 0; k < H1 / 4; ++k) {
        f32x4 a = hv[k];
        f32x4 wq = wv[k];
        s += a[0] * wq[0] + a[1] * wq[1] + a[2] * wq[2] + a[3] * wq[3];
    }
    out[(size_t)b * 32 + o]      = s;
    out[(size_t)b * 32 + 16 + o] = s;
}

// ===========================================================================
extern "C" void kernel_launch(void* const* d_in, const int* in_sizes, int n_in,
                              void* d_out, int out_size, void* d_ws, size_t ws_size,
                              hipStream_t stream)
{
    const float* x    = (const float*)d_in[0];
    const float* Wih0 = (const float*)d_in[1];
    const float* Whh0 = (const float*)d_in[2];
    const float* b0   = (const float*)d_in[3];
    const float* Wih1 = (const float*)d_in[4];
    const float* Whh1 = (const float*)d_in[5];
    const float* b1   = (const float*)d_in[6];
    const float* dWih = (const float*)d_in[7];
    const float* dWhh = (const float*)d_in[8];
    const float* db   = (const float*)d_in[9];
    const float* Wout = (const float*)d_in[10];
    const float* bout = (const float*)d_in[11];

    const size_t NEED =
        (size_t)16777216      /* xpair  */
      + (size_t)119537664     /* wpair  */
      + (size_t)16777216      /* g0,g1  */
      + (size_t)4194304       /* c0,c1  */
      + (size_t)6291456;      /* h pairs*/

    dim3 blk(256);

    if (ws_size >= NEED) {
        // ---------------- new path ----------------
        char* w8 = (char*)d_ws;
        __bf16* xp = (__bf16*)w8;
        __bf16* wp = (__bf16*)(w8 + 16777216);
        float* g0b = (float*)(w8 + 16777216 + 119537664);
        float* g1b = g0b + (size_t)BATCH * FOURH;
        float* c0  = g1b + (size_t)BATCH * FOURH;
        float* c1  = c0 + (size_t)BATCH * H1;
        __bf16* hp0a = (__bf16*)(c1 + (size_t)BATCH * H1);
        __bf16* hp0b = hp0a + (size_t)BATCH * 2048;
        __bf16* hp1  = hp0b + (size_t)BATCH * 2048;

        __bf16* Wih0p  = wp;
        __bf16* Whh0p  = Wih0p + (size_t)4096 * 256;
        __bf16* Wih1p  = Whh0p + (size_t)4096 * 2048;
        __bf16* Whh1p  = Wih1p + (size_t)4096 * 2048;
        __bf16* dWih0p = Whh1p + (size_t)4096 * 2048;
        __bf16* dWhh0p = dWih0p + (size_t)4096 * 2048;
        __bf16* dWih1p = dWhh0p + (size_t)4096 * 2048;
        __bf16* dWhh1p = dWih1p + (size_t)4096 * 2048;

        hipFuncSetAttribute(reinterpret_cast<const void*>(gemm_pair_lds),
                            hipFuncAttributeMaxDynamicSharedMemorySize, 98304);

        auto conv = [&](const float* s, __bf16* d, int R, int shift) {
            int total4 = R * (1 << shift);
            conv_pair_k<<<(total4 + 255) / 256, blk, 0, stream>>>(s, d, total4, shift);
        };
        conv(x, xp, BATCH * SEQ, 5);           // K=128
        conv(Wih0, Wih0p, 4096, 5);
        conv(Whh0, Whh0p, 4096, 8);            // K=1024
        conv(Wih1, Wih1p, 4096, 8);
        conv(Whh1, Whh1p, 4096, 8);
        conv(dWih,                      dWih0p, 4096, 8);
        conv(dWih + (size_t)4096 * 1024, dWih1p, 4096, 8);
        conv(dWhh,                      dWhh0p, 4096, 8);
        conv(dWhh + (size_t)4096 * 1024, dWhh1p, 4096, 8);

        hipMemsetAsync(hp0a, 0, (size_t)BATCH * 2048 * 2, stream);
        hipMemsetAsync(hp1,  0, (size_t)BATCH * 2048 * 2, stream);
        hipMemsetAsync(c0,   0, (size_t)BATCH * H1 * 4, stream);
        hipMemsetAsync(c1,   0, (size_t)BATCH * H1 * 4, stream);

        dim3 ggrid(32, 4, 2);
        dim3 cgrid((BATCH * H1) / 256);

        __bf16* hc = hp0a;
        __bf16* hn = hp0b;

        for (int t = 0; t < SEQ; ++t) {
            gemm_pair_lds<<<ggrid, blk, 98304, stream>>>(
                xp + t * 256, SEQ * 256, 128, 128, Wih0p, 256,
                hc, 2048, 1024, 1024, Whh0p, 2048, g0b, g1b);
            lstm_cell2_k<<<cgrid, blk, 0, stream>>>(g0b, g1b, b0, c0, hn);
            gemm_pair_lds<<<ggrid, blk, 98304, stream>>>(
                hn, 2048, 1024, 1024, Wih1p, 2048,
                hp1, 2048, 1024, 1024, Whh1p, 2048, g0b, g1b);
            lstm_cell2_k<<<cgrid, blk, 0, stream>>>(g0b, g1b, b1, c1, hp1);
            __bf16* tmp = hc; hc = hn; hn = tmp;
        }

        for (int s = 0; s < TDEC; ++s) {
            gemm_pair_lds<<<ggrid, blk, 98304, stream>>>(
                hp1, 2048, 1024, 1024, dWih0p, 2048,
                hc, 2048, 1024, 1024, dWhh0p, 2048, g0b, g1b);
            lstm_cell2_k<<<cgrid, blk, 0, stream>>>(g0b, g1b, db, c0, hn);
            gemm_pair_lds<<<ggrid, blk, 98304, stream>>>(
                hn, 2048, 1024, 1024, dWih1p, 2048,
                hp1, 2048, 1024, 1024, dWhh1p, 2048, g0b, g1b);
            lstm_cell2_k<<<cgrid, blk, 0, stream>>>(g0b, g1b, db + FOURH, c1, hp1);
            __bf16* tmp = hc; hc = hn; hn = tmp;
        }

        head2_k<<<dim3(32), blk, 0, stream>>>(hp1, Wout, bout, (float*)d_out);
    } else {
        // ---------------- fallback: round-1 proven path ----------------
        float* ws    = (float*)d_ws;
        float* gates = ws;
        float* h0a   = gates + (size_t)BATCH * FOURH;
        float* h0b   = h0a + (size_t)BATCH * H1;
        float* h1    = h0b + (size_t)BATCH * H1;
        float* c0    = h1 + (size_t)BATCH * H1;
        float* c1    = c0 + (size_t)BATCH * H1;

        const size_t sbytes = (size_t)BATCH * H1 * sizeof(float);
        hipMemsetAsync(h0a, 0, sbytes, stream);
        hipMemsetAsync(h1, 0, sbytes, stream);
        hipMemsetAsync(c0, 0, sbytes, stream);
        hipMemsetAsync(c1, 0, sbytes, stream);

        dim3 grid(FOURH / BN, BATCH / BM);
        dim3 cgrid((BATCH * H1) / 256);

        float* hc = h0a;
        float* hn = h0b;

        for (int t = 0; t < SEQ; ++t) {
            gemm2_split<<<grid, blk, 0, stream>>>(x + (size_t)t * DIN, SEQ * DIN, Wih0, DIN,
                                                  hc, H1, Whh0, H1, b0, gates);
            lstm_cell_k<<<cgrid, blk, 0, stream>>>(gates, c0, hn);
            gemm2_split<<<grid, blk, 0, stream>>>(hn, H1, Wih1, H1,
                                                  h1, H1, Whh1, H1, b1, gates);
            lstm_cell_k<<<cgrid, blk, 0, stream>>>(gates, c1, h1);
            float* tmp = hc; hc = hn; hn = tmp;
        }

        const float* dWih1 = dWih + (size_t)FOURH * H1;
        const float* dWhh1 = dWhh + (size_t)FOURH * H1;
        const float* db1v  = db + FOURH;
        for (int s = 0; s < TDEC; ++s) {
            gemm2_split<<<grid, blk, 0, stream>>>(h1, H1, dWih, H1,
                                                  hc, H1, dWhh, H1, db, gates);
            lstm_cell_k<<<cgrid, blk, 0, stream>>>(gates, c0, hn);
            gemm2_split<<<grid, blk, 0, stream>>>(hn, H1, dWih1, H1,
                                                  h1, H1, dWhh1, H1, db1v, gates);
            lstm_cell_k<<<cgrid, blk, 0, stream>>>(gates, c1, h1);
            float* tmp = hc; hc = hn; hn = tmp;
        }

        head_k<<<dim3(32), blk, 0, stream>>>(h1, Wout, bout, (float*)d_out);
    }
}

// Round 4
// 5959.031 us; speedup vs baseline: 1.1840x; 1.0131x over previous
//
#include <hip/hip_runtime.h>
#include <hip/hip_bf16.h>

#define H1 1024
#define FOURH 4096
#define BATCH 512
#define SEQ 64
#define DIN 128
#define TDEC 8

typedef float f32x4 __attribute__((ext_vector_type(4)));
typedef __bf16 bf16x8 __attribute__((ext_vector_type(8)));

// global->LDS direct, 16B per lane. LDS dest is wave-uniform base + lane*16.
__device__ __forceinline__ void gl_lds16(const void* g, void* l) {
    __builtin_amdgcn_global_load_lds(
        (const __attribute__((address_space(1))) unsigned int*)g,
        (__attribute__((address_space(3))) unsigned int*)l, 16, 0, 0);
}

// ---------------------------------------------------------------------------
// Partial gates: out = A0[512][*]·B0[4096][*]^T + A1·B1^T  (fp32 in, fp32 out)
// fp32 operands staged to LDS (global_load_lds, XOR-swizzled source), split
// to bf16 hi/lo IN-REGISTER, 3-term MFMA (hh + hl + lh) per output fragment.
// Tile BM=BN=128, BK=32(f32); 4 waves, wave tile 64x64 (4x4 16x16x32 frags).
// K-split 2 via blockIdx.z -> g0/g1 partial buffers (bias added in cell).
// Triple-buffered LDS (3 x (16KB A + 16KB B) = 96KB dynamic).
// ---------------------------------------------------------------------------
__global__ __launch_bounds__(256) void gemm_f32split(
    const float* __restrict__ a0, int lda0, const float* __restrict__ b0, int ldb0, int kh0,
    const float* __restrict__ a1, int lda1, const float* __restrict__ b1, int ldb1, int kh1,
    float* __restrict__ g0, float* __restrict__ g1)
{
    extern __shared__ char smem[];            // 3 * (16KB + 16KB)
    const int tid  = threadIdx.x;
    const int lane = tid & 63;
    const int w    = tid >> 6;                // wave 0..3
    const int wm   = w >> 1, wn = w & 1;
    const int bn   = blockIdx.x, bm = blockIdx.y, ks = blockIdx.z;
    float* out = ks ? g1 : g0;

    const int n0 = kh0 >> 5, n1 = kh1 >> 5;   // 32-K chunks per pair
    const int n  = n0 + n1;
    // pre-offset by K-split half
    const float* A0 = a0 + ks * kh0;
    const float* B0 = b0 + ks * kh0;
    const float* A1 = a1 + ks * kh1;
    const float* B1 = b1 + ks * kh1;

    // staging geometry: wave w, round j covers tile rows [(j*4+w)*8, +8)
    const int rsub = lane >> 3;               // 0..7 (row within 8-row stripe)
    const int gsw  = (lane & 7) ^ rsub;       // swizzled source granule (16B)
    int rowj[4];
#pragma unroll
    for (int j = 0; j < 4; ++j) rowj[j] = (j * 4 + w) * 8 + rsub;

    auto stage = [&](int ii, int buf) {
        const float* A; const float* B; int lda, ldb, kk;
        if (ii < n0) { A = A0; B = B0; lda = lda0; ldb = ldb0; kk = ii << 5; }
        else         { A = A1; B = B1; lda = lda1; ldb = ldb1; kk = (ii - n0) << 5; }
        const float* aU = A + (size_t)(bm * 128) * lda + kk;
        const float* bU = B + (size_t)(bn * 128) * ldb + kk;
        char* lA = smem + buf * 32768;
        char* lB = lA + 16384;
#pragma unroll
        for (int j = 0; j < 4; ++j) {
            gl_lds16(aU + (size_t)rowj[j] * lda + gsw * 4, lA + (j * 4 + w) * 1024);
            gl_lds16(bU + (size_t)rowj[j] * ldb + gsw * 4, lB + (j * 4 + w) * 1024);
        }
    };

    f32x4 acc[4][4];
#pragma unroll
    for (int mf = 0; mf < 4; ++mf)
#pragma unroll
        for (int nf = 0; nf < 4; ++nf)
            acc[mf][nf] = (f32x4){0.f, 0.f, 0.f, 0.f};

    int rA[4], rB[4];
#pragma unroll
    for (int f = 0; f < 4; ++f) {
        rA[f] = wm * 64 + f * 16 + (lane & 15);
        rB[f] = wn * 64 + f * 16 + (lane & 15);
    }
    const int hi4 = lane >> 4;                // k-slot 0..3 (8 elems each)
    const int g2  = hi4 * 2;                  // first granule of the k-slice

    stage(0, 0);
    stage(1, 1);

    int buf = 0;
    for (int i = 0; i < n; ++i) {
        if (i < n - 1) asm volatile("s_waitcnt vmcnt(8)" ::: "memory");
        else           asm volatile("s_waitcnt vmcnt(0)" ::: "memory");
        __builtin_amdgcn_sched_barrier(0);
        __builtin_amdgcn_s_barrier();
        __builtin_amdgcn_sched_barrier(0);

        if (i + 2 < n) {
            int b2 = buf + 2; if (b2 >= 3) b2 -= 3;
            stage(i + 2, b2);
        }

        char* lA = smem + buf * 32768;
        char* lB = lA + 16384;

        // read f32 fragments (2 x b128 each, XOR-swizzled), split, 3-term MFMA
        bf16x8 ah[4], al[4], bh[4], bl[4];
#pragma unroll
        for (int f = 0; f < 4; ++f) {
            {
                int r = rA[f], s = r & 7;
                f32x4 v0 = *(const f32x4*)(lA + r * 128 + ((g2    ) ^ s) * 16);
                f32x4 v1 = *(const f32x4*)(lA + r * 128 + ((g2 + 1) ^ s) * 16);
#pragma unroll
                for (int e = 0; e < 4; ++e) {
                    __bf16 h0 = (__bf16)v0[e];
                    ah[f][e] = h0; al[f][e] = (__bf16)(v0[e] - (float)h0);
                    __bf16 h1 = (__bf16)v1[e];
                    ah[f][e + 4] = h1; al[f][e + 4] = (__bf16)(v1[e] - (float)h1);
                }
            }
            {
                int r = rB[f], s = r & 7;
                f32x4 v0 = *(const f32x4*)(lB + r * 128 + ((g2    ) ^ s) * 16);
                f32x4 v1 = *(const f32x4*)(lB + r * 128 + ((g2 + 1) ^ s) * 16);
#pragma unroll
                for (int e = 0; e < 4; ++e) {
                    __bf16 h0 = (__bf16)v0[e];
                    bh[f][e] = h0; bl[f][e] = (__bf16)(v0[e] - (float)h0);
                    __bf16 h1 = (__bf16)v1[e];
                    bh[f][e + 4] = h1; bl[f][e + 4] = (__bf16)(v1[e] - (float)h1);
                }
            }
        }
#pragma unroll
        for (int mf = 0; mf < 4; ++mf)
#pragma unroll
            for (int nf = 0; nf < 4; ++nf) {
                acc[mf][nf] = __builtin_amdgcn_mfma_f32_16x16x32_bf16(
                    ah[mf], bh[nf], acc[mf][nf], 0, 0, 0);
                acc[mf][nf] = __builtin_amdgcn_mfma_f32_16x16x32_bf16(
                    ah[mf], bl[nf], acc[mf][nf], 0, 0, 0);
                acc[mf][nf] = __builtin_amdgcn_mfma_f32_16x16x32_bf16(
                    al[mf], bh[nf], acc[mf][nf], 0, 0, 0);
            }
        __builtin_amdgcn_sched_barrier(0);
        buf = buf + 1; if (buf >= 3) buf -= 3;
    }

    // epilogue: C layout col=lane&15, row=(lane>>4)*4 + jj (m89-verified)
#pragma unroll
    for (int mf = 0; mf < 4; ++mf)
#pragma unroll
        for (int nf = 0; nf < 4; ++nf) {
            int row0 = bm * 128 + wm * 64 + mf * 16 + hi4 * 4;
            int col  = bn * 128 + wn * 64 + nf * 16 + (lane & 15);
#pragma unroll
            for (int jj = 0; jj < 4; ++jj)
                out[(size_t)(row0 + jj) * FOURH + col] = acc[mf][nf][jj];
        }
}

// ---------------------------------------------------------------------------
// Cell: gates = g0 + g1 + bias (i,f,g,o), update c, h (fp32). f32x4 per thread.
// ---------------------------------------------------------------------------
__global__ __launch_bounds__(256) void lstm_cell_k(
    const float* __restrict__ g0, const float* __restrict__ g1,
    const float* __restrict__ bias,
    float* __restrict__ c, float* __restrict__ h)
{
    int q  = blockIdx.x * 256 + threadIdx.x;       // 0 .. 512*1024/4-1
    int b  = q >> 8;                               // 256 f32x4 per row
    int u4 = q & 255;
    size_t base = (size_t)b * FOURH + u4 * 4;
    f32x4 gi = *(const f32x4*)(g0 + base)          + *(const f32x4*)(g1 + base)          + *(const f32x4*)(bias + u4 * 4);
    f32x4 gf = *(const f32x4*)(g0 + base + H1)     + *(const f32x4*)(g1 + base + H1)     + *(const f32x4*)(bias + H1 + u4 * 4);
    f32x4 gg = *(const f32x4*)(g0 + base + 2 * H1) + *(const f32x4*)(g1 + base + 2 * H1) + *(const f32x4*)(bias + 2 * H1 + u4 * 4);
    f32x4 go = *(const f32x4*)(g0 + base + 3 * H1) + *(const f32x4*)(g1 + base + 3 * H1) + *(const f32x4*)(bias + 3 * H1 + u4 * 4);
    size_t sidx = (size_t)b * H1 + u4 * 4;
    f32x4 cv = *(const f32x4*)(c + sidx);
    f32x4 cn, hn;
#pragma unroll
    for (int e = 0; e < 4; ++e) {
        float si = 1.f / (1.f + expf(-gi[e]));
        float sf = 1.f / (1.f + expf(-gf[e]));
        float so = 1.f / (1.f + expf(-go[e]));
        float cc = sf * cv[e] + si * tanhf(gg[e]);
        cn[e] = cc;
        hn[e] = so * tanhf(cc);
    }
    *(f32x4*)(c + sidx) = cn;
    *(f32x4*)(h + sidx) = hn;
}

// ---------------------------------------------------------------------------
// Output head: out[b][o] = h[b]·W_out[o] + b_out[o], duplicated at +16.
// ---------------------------------------------------------------------------
__global__ __launch_bounds__(256) void head_k(
    const float* __restrict__ h, const float* __restrict__ W,
    const float* __restrict__ bo, float* __restrict__ out)
{
    int idx = blockIdx.x * 256 + threadIdx.x;      // 0..8191
    int b = idx >> 4, o = idx & 15;
    const f32x4* hv = (const f32x4*)(h + (size_t)b * H1);
    const f32x4* wv = (const f32x4*)(W + (size_t)o * H1);
    float s = bo[o];
#pragma unroll 4
    for (int k = 0; k < H1 / 4; ++k) {
        f32x4 a = hv[k];
        f32x4 wq = wv[k];
        s += a[0] * wq[0] + a[1] * wq[1] + a[2] * wq[2] + a[3] * wq[3];
    }
    out[(size_t)b * 32 + o]      = s;
    out[(size_t)b * 32 + 16 + o] = s;
}

// ===========================================================================
extern "C" void kernel_launch(void* const* d_in, const int* in_sizes, int n_in,
                              void* d_out, int out_size, void* d_ws, size_t ws_size,
                              hipStream_t stream)
{
    const float* x    = (const float*)d_in[0];
    const float* Wih0 = (const float*)d_in[1];
    const float* Whh0 = (const float*)d_in[2];
    const float* b0   = (const float*)d_in[3];
    const float* Wih1 = (const float*)d_in[4];
    const float* Whh1 = (const float*)d_in[5];
    const float* b1   = (const float*)d_in[6];
    const float* dWih = (const float*)d_in[7];
    const float* dWhh = (const float*)d_in[8];
    const float* db   = (const float*)d_in[9];
    const float* Wout = (const float*)d_in[10];
    const float* bout = (const float*)d_in[11];

    float* ws  = (float*)d_ws;
    float* g0b = ws;                               // 512*4096
    float* g1b = g0b + (size_t)BATCH * FOURH;      // 512*4096
    float* h0a = g1b + (size_t)BATCH * FOURH;      // 512*1024 each below
    float* h0b = h0a + (size_t)BATCH * H1;
    float* h1  = h0b + (size_t)BATCH * H1;
    float* c0  = h1 + (size_t)BATCH * H1;
    float* c1  = c0 + (size_t)BATCH * H1;

    const size_t sbytes = (size_t)BATCH * H1 * sizeof(float);
    hipMemsetAsync(h0a, 0, sbytes, stream);
    hipMemsetAsync(h1, 0, sbytes, stream);
    hipMemsetAsync(c0, 0, sbytes, stream);
    hipMemsetAsync(c1, 0, sbytes, stream);

    hipFuncSetAttribute(reinterpret_cast<const void*>(gemm_f32split),
                        hipFuncAttributeMaxDynamicSharedMemorySize, 98304);

    dim3 blk(256);
    dim3 ggrid(FOURH / 128, BATCH / 128, 2);       // (32, 4, 2)
    dim3 cgrid((BATCH * H1) / (256 * 4));          // 512 (f32x4 per thread)

    float* hc = h0a;   // layer-0 h (current)
    float* hn = h0b;   // layer-0 h (next)

    // ---- encoder: layers interleaved per timestep ----
    for (int t = 0; t < SEQ; ++t) {
        gemm_f32split<<<ggrid, blk, 98304, stream>>>(
            x + (size_t)t * DIN, SEQ * DIN, Wih0, DIN, DIN / 2,
            hc, H1, Whh0, H1, H1 / 2, g0b, g1b);
        lstm_cell_k<<<cgrid, blk, 0, stream>>>(g0b, g1b, b0, c0, hn);
        gemm_f32split<<<ggrid, blk, 98304, stream>>>(
            hn, H1, Wih1, H1, H1 / 2,
            h1, H1, Whh1, H1, H1 / 2, g0b, g1b);
        lstm_cell_k<<<cgrid, blk, 0, stream>>>(g0b, g1b, b1, c1, h1);
        float* tmp = hc; hc = hn; hn = tmp;
    }

    // ---- decoder ----
    const float* dWih1 = dWih + (size_t)FOURH * H1;
    const float* dWhh1 = dWhh + (size_t)FOURH * H1;
    const float* db1v  = db + FOURH;
    for (int s = 0; s < TDEC; ++s) {
        gemm_f32split<<<ggrid, blk, 98304, stream>>>(
            h1, H1, dWih, H1, H1 / 2,
            hc, H1, dWhh, H1, H1 / 2, g0b, g1b);
        lstm_cell_k<<<cgrid, blk, 0, stream>>>(g0b, g1b, db, c0, hn);
        gemm_f32split<<<ggrid, blk, 98304, stream>>>(
            hn, H1, dWih1, H1, H1 / 2,
            h1, H1, dWhh1, H1, H1 / 2, g0b, g1b);
        lstm_cell_k<<<cgrid, blk, 0, stream>>>(g0b, g1b, db1v, c1, h1);
        float* tmp = hc; hc = hn; hn = tmp;
    }

    // ---- output head ----
    head_k<<<dim3(32), blk, 0, stream>>>(h1, Wout, bout, (float*)d_out);
}